// Round 1
// baseline (2212.991 us; speedup 1.0000x reference)
//
#include <hip/hip_runtime.h>

#define N_NODES 50000
#define N_EDGES 800000
#define N_GRAPHS 512
#define D 64

// Scatter-add: 16 threads per edge, each handles a float4 (4 dims).
__global__ __launch_bounds__(256) void scatter_kernel(
    const float* __restrict__ x, const int* __restrict__ src,
    const int* __restrict__ dst, float* __restrict__ agg, int n_edges)
{
    int t = blockIdx.x * blockDim.x + threadIdx.x;
    int e = t >> 4;
    if (e >= n_edges) return;
    int q = t & 15;
    int s = src[e], d0 = dst[e];
    const float4 v = *(const float4*)(x + (size_t)s * D + q * 4);
    float* out = agg + (size_t)d0 * D + q * 4;
    atomicAdd(out + 0, v.x);
    atomicAdd(out + 1, v.y);
    atomicAdd(out + 2, v.z);
    atomicAdd(out + 3, v.w);
}

__global__ __launch_bounds__(256) void count_kernel(
    const int* __restrict__ batch, float* __restrict__ cnt, int n_nodes)
{
    int i = blockIdx.x * blockDim.x + threadIdx.x;
    if (i < n_nodes) atomicAdd(&cnt[batch[i]], 1.0f);
}

// Fused GIN MLP: in = agg + x; h = relu(in@wa + ba); y = relu(h@wb + bb).
// Block = 256 threads = 4 waves, 64 nodes per block. Wave lane = output dim.
// Weight reads are stride-1 LDS (2-way, free); input reads are wave-uniform
// broadcasts. Writes coalesced. Layer 3 pools via atomics instead of writing.
__global__ __launch_bounds__(256) void mlp_kernel(
    const float* __restrict__ agg, const float* __restrict__ xin,
    const float* __restrict__ wa, const float* __restrict__ ba,
    const float* __restrict__ wb, const float* __restrict__ bb,
    float* __restrict__ xout,
    const int* __restrict__ batch, float* __restrict__ poolsum,
    int n_nodes, int do_pool)
{
    __shared__ float sWa[D * D];
    __shared__ float sWb[D * D];
    __shared__ float sIn[64 * D];
    __shared__ float sH[64 * D];
    const int t = threadIdx.x;
    const int node0 = blockIdx.x * 64;

    for (int i = t; i < D * D / 4; i += 256) {
        ((float4*)sWa)[i] = ((const float4*)wa)[i];
        ((float4*)sWb)[i] = ((const float4*)wb)[i];
    }
    for (int i = t; i < 64 * D / 4; i += 256) {
        int n = node0 + (i >> 4);
        float4 v = make_float4(0.f, 0.f, 0.f, 0.f);
        if (n < n_nodes) {
            float4 a = ((const float4*)agg)[(size_t)node0 * 16 + i];
            float4 b = ((const float4*)xin)[(size_t)node0 * 16 + i];
            v = make_float4(a.x + b.x, a.y + b.y, a.z + b.z, a.w + b.w);
        }
        ((float4*)sIn)[i] = v;
    }
    __syncthreads();

    const int od = t & 63;
    const int nb = t >> 6;  // 0..3; node j handled = nb + 4*j
    float acc[16];
    {
        const float b0 = ba[od];
        #pragma unroll
        for (int j = 0; j < 16; ++j) acc[j] = b0;
        for (int k = 0; k < D; ++k) {
            const float w = sWa[k * D + od];
            #pragma unroll
            for (int j = 0; j < 16; ++j)
                acc[j] = fmaf(sIn[(nb + j * 4) * D + k], w, acc[j]);
        }
    }
    #pragma unroll
    for (int j = 0; j < 16; ++j)
        sH[(nb + j * 4) * D + od] = fmaxf(acc[j], 0.0f);
    __syncthreads();

    {
        const float b1 = bb[od];
        #pragma unroll
        for (int j = 0; j < 16; ++j) acc[j] = b1;
        for (int k = 0; k < D; ++k) {
            const float w = sWb[k * D + od];
            #pragma unroll
            for (int j = 0; j < 16; ++j)
                acc[j] = fmaf(sH[(nb + j * 4) * D + k], w, acc[j]);
        }
    }

    if (do_pool) {
        #pragma unroll
        for (int j = 0; j < 16; ++j) {
            int n = node0 + nb + j * 4;
            if (n < n_nodes) {
                float v = fmaxf(acc[j], 0.0f);
                atomicAdd(&poolsum[batch[n] * D + od], v);
            }
        }
    } else {
        #pragma unroll
        for (int j = 0; j < 16; ++j) {
            int n = node0 + nb + j * 4;
            if (n < n_nodes)
                xout[(size_t)n * D + od] = fmaxf(acc[j], 0.0f);
        }
    }
}

// One wave per graph: out[g] = dot(poolsum[g]/max(cnt,1), wl) + bl.
__global__ __launch_bounds__(64) void final_kernel(
    const float* __restrict__ poolsum, const float* __restrict__ cnt,
    const float* __restrict__ wl, const float* __restrict__ bl,
    float* __restrict__ out)
{
    int g = blockIdx.x;
    int d = threadIdx.x;
    float c = fmaxf(cnt[g], 1.0f);
    float v = (poolsum[g * D + d] / c) * wl[d];
    for (int off = 32; off > 0; off >>= 1)
        v += __shfl_down(v, off, 64);
    if (d == 0) out[g] = v + bl[0];
}

extern "C" void kernel_launch(void* const* d_in, const int* in_sizes, int n_in,
                              void* d_out, int out_size, void* d_ws, size_t ws_size,
                              hipStream_t stream) {
    const float* feat = (const float*)d_in[0];
    const int*   ei   = (const int*)d_in[1];
    const int*   batch= (const int*)d_in[2];
    const float* w1a = (const float*)d_in[3];
    const float* b1a = (const float*)d_in[4];
    const float* w1b = (const float*)d_in[5];
    const float* b1b = (const float*)d_in[6];
    const float* w2a = (const float*)d_in[7];
    const float* b2a = (const float*)d_in[8];
    const float* w2b = (const float*)d_in[9];
    const float* b2b = (const float*)d_in[10];
    const float* w3a = (const float*)d_in[11];
    const float* b3a = (const float*)d_in[12];
    const float* w3b = (const float*)d_in[13];
    const float* b3b = (const float*)d_in[14];
    const float* wl  = (const float*)d_in[15];
    const float* bl  = (const float*)d_in[16];
    const int* src = ei;
    const int* dst = ei + N_EDGES;

    float* agg     = (float*)d_ws;
    float* buf0    = agg  + (size_t)N_NODES * D;
    float* buf1    = buf0 + (size_t)N_NODES * D;
    float* poolsum = buf1 + (size_t)N_NODES * D;
    float* cnt     = poolsum + N_GRAPHS * D;
    float* out     = (float*)d_out;

    const size_t aggBytes = (size_t)N_NODES * D * sizeof(float);
    dim3 blk(256);
    const int scatterGrid = (N_EDGES * 16 + 255) / 256;
    const int mlpGrid = (N_NODES + 63) / 64;

    // layer 1
    hipMemsetAsync(agg, 0, aggBytes, stream);
    scatter_kernel<<<scatterGrid, blk, 0, stream>>>(feat, src, dst, agg, N_EDGES);
    mlp_kernel<<<mlpGrid, blk, 0, stream>>>(agg, feat, w1a, b1a, w1b, b1b,
                                            buf0, nullptr, nullptr, N_NODES, 0);
    // layer 2
    hipMemsetAsync(agg, 0, aggBytes, stream);
    scatter_kernel<<<scatterGrid, blk, 0, stream>>>(buf0, src, dst, agg, N_EDGES);
    mlp_kernel<<<mlpGrid, blk, 0, stream>>>(agg, buf0, w2a, b2a, w2b, b2b,
                                            buf1, nullptr, nullptr, N_NODES, 0);
    // layer 3 + pooling
    hipMemsetAsync(agg, 0, aggBytes, stream);
    hipMemsetAsync(poolsum, 0, (size_t)(N_GRAPHS * D + N_GRAPHS) * sizeof(float), stream);
    scatter_kernel<<<scatterGrid, blk, 0, stream>>>(buf1, src, dst, agg, N_EDGES);
    count_kernel<<<(N_NODES + 255) / 256, blk, 0, stream>>>(batch, cnt, N_NODES);
    mlp_kernel<<<mlpGrid, blk, 0, stream>>>(agg, buf1, w3a, b3a, w3b, b3b,
                                            nullptr, batch, poolsum, N_NODES, 1);
    final_kernel<<<N_GRAPHS, dim3(64), 0, stream>>>(poolsum, cnt, wl, bl, out);
}

// Round 2
// 327.616 us; speedup vs baseline: 6.7548x; 6.7548x over previous
//
#include <hip/hip_runtime.h>

#define N_NODES 50000
#define N_EDGES 800000
#define N_GRAPHS 512
#define D 64
#define NPB 32  // nodes per block in the fused layer kernel

// ---------------- CSR build (by dst) ----------------

__global__ __launch_bounds__(256) void hist_kernel(
    const int* __restrict__ dst, int* __restrict__ deg)
{
    int e = blockIdx.x * blockDim.x + threadIdx.x;
    if (e < N_EDGES) atomicAdd(&deg[dst[e]], 1);
}

// per-block exclusive scan of deg; block sums out
__global__ __launch_bounds__(256) void scan1_kernel(
    const int* __restrict__ deg, int* __restrict__ excl,
    int* __restrict__ bsum, int n)
{
    __shared__ int s[256];
    int t = threadIdx.x;
    int i = blockIdx.x * 256 + t;
    int v = (i < n) ? deg[i] : 0;
    s[t] = v;
    __syncthreads();
    for (int off = 1; off < 256; off <<= 1) {
        int x = (t >= off) ? s[t - off] : 0;
        __syncthreads();
        s[t] += x;
        __syncthreads();
    }
    if (i < n) excl[i] = s[t] - v;
    if (t == 255) bsum[blockIdx.x] = s[255];
}

// single-block exclusive scan of block sums (nblocks <= 256)
__global__ __launch_bounds__(256) void scan2_kernel(
    const int* __restrict__ bsum, int* __restrict__ boffs, int nblocks)
{
    __shared__ int s[256];
    int t = threadIdx.x;
    int v = (t < nblocks) ? bsum[t] : 0;
    s[t] = v;
    __syncthreads();
    for (int off = 1; off < 256; off <<= 1) {
        int x = (t >= off) ? s[t - off] : 0;
        __syncthreads();
        s[t] += x;
        __syncthreads();
    }
    if (t < nblocks) boffs[t] = s[t] - v;
}

// add block offsets; produce rowptr and cursor copy
__global__ __launch_bounds__(256) void scan3_kernel(
    int* __restrict__ rowptr, const int* __restrict__ boffs,
    int* __restrict__ cursor, int n)
{
    int i = blockIdx.x * 256 + threadIdx.x;
    if (i < n) {
        int r = rowptr[i] + boffs[blockIdx.x];
        rowptr[i] = r;
        cursor[i] = r;
    }
    if (blockIdx.x == 0 && threadIdx.x == 0) rowptr[n] = N_EDGES;
}

__global__ __launch_bounds__(256) void fill_kernel(
    const int* __restrict__ src, const int* __restrict__ dst,
    int* __restrict__ cursor, int* __restrict__ eidx)
{
    int e = blockIdx.x * blockDim.x + threadIdx.x;
    if (e < N_EDGES) {
        int pos = atomicAdd(&cursor[dst[e]], 1);
        eidx[pos] = src[e];
    }
}

__global__ __launch_bounds__(256) void count_kernel(
    const int* __restrict__ batch, float* __restrict__ cnt)
{
    int i = blockIdx.x * blockDim.x + threadIdx.x;
    if (i < N_NODES) atomicAdd(&cnt[batch[i]], 1.0f);
}

// ---------------- Fused gather + GIN MLP ----------------
// Block = 256 threads, NPB=32 nodes. Gather: 16 threads/node (float4 slices),
// CSR rows contiguous per node, eidx prefetch pipelines the dependent loads.
// MLP: lane od = output dim; weight reads stride-1 LDS (free 2-way), input
// reads wave-uniform broadcast. sIn reused for hidden tile (40KB LDS total).
__global__ __launch_bounds__(256) void gin_layer(
    const float* __restrict__ x,
    const int* __restrict__ rowptr, const int* __restrict__ eidx,
    const float* __restrict__ wa, const float* __restrict__ ba,
    const float* __restrict__ wb, const float* __restrict__ bb,
    float* __restrict__ xout,
    const int* __restrict__ batch, float* __restrict__ poolsum,
    int do_pool)
{
    __shared__ float sWa[D * D];
    __shared__ float sWb[D * D];
    __shared__ float sIn[NPB * D];
    const int t = threadIdx.x;
    const int node0 = blockIdx.x * NPB;

    for (int i = t; i < D * D / 4; i += 256) {
        ((float4*)sWa)[i] = ((const float4*)wa)[i];
        ((float4*)sWb)[i] = ((const float4*)wb)[i];
    }

    const float4* x4 = (const float4*)x;
    #pragma unroll
    for (int pass = 0; pass < 2; ++pass) {
        int ln = pass * 16 + (t >> 4);   // local node 0..31
        int q  = t & 15;                 // float4 slice
        int n  = node0 + ln;
        float4 acc = make_float4(0.f, 0.f, 0.f, 0.f);
        if (n < N_NODES) {
            acc = x4[(size_t)n * 16 + q];
            int e0 = rowptr[n], e1 = rowptr[n + 1];
            int sn = (e0 < e1) ? eidx[e0] : 0;
            for (int e = e0; e < e1;) {
                int sc = sn;
                ++e;
                if (e < e1) sn = eidx[e];
                float4 v = x4[(size_t)sc * 16 + q];
                acc.x += v.x; acc.y += v.y; acc.z += v.z; acc.w += v.w;
            }
        }
        ((float4*)sIn)[ln * 16 + q] = acc;
    }
    __syncthreads();

    const int od = t & 63;
    const int nb = t >> 6;  // node j handled = nb + 4*j
    float acc[8];
    {
        const float b0 = ba[od];
        #pragma unroll
        for (int j = 0; j < 8; ++j) acc[j] = b0;
        for (int k = 0; k < D; ++k) {
            const float w = sWa[k * D + od];
            #pragma unroll
            for (int j = 0; j < 8; ++j)
                acc[j] = fmaf(sIn[(nb + j * 4) * D + k], w, acc[j]);
        }
    }
    __syncthreads();
    #pragma unroll
    for (int j = 0; j < 8; ++j)
        sIn[(nb + j * 4) * D + od] = fmaxf(acc[j], 0.0f);
    __syncthreads();
    {
        const float b1 = bb[od];
        #pragma unroll
        for (int j = 0; j < 8; ++j) acc[j] = b1;
        for (int k = 0; k < D; ++k) {
            const float w = sWb[k * D + od];
            #pragma unroll
            for (int j = 0; j < 8; ++j)
                acc[j] = fmaf(sIn[(nb + j * 4) * D + k], w, acc[j]);
        }
    }

    if (do_pool) {
        // batch is sorted: run-length compress pooling atomics
        int curg = -1; float run = 0.f;
        #pragma unroll
        for (int j = 0; j < 8; ++j) {
            int n = node0 + nb + j * 4;
            if (n < N_NODES) {
                float v = fmaxf(acc[j], 0.0f);
                int g = batch[n];
                if (g != curg) {
                    if (curg >= 0) atomicAdd(&poolsum[curg * D + od], run);
                    curg = g; run = v;
                } else {
                    run += v;
                }
            }
        }
        if (curg >= 0) atomicAdd(&poolsum[curg * D + od], run);
    } else {
        #pragma unroll
        for (int j = 0; j < 8; ++j) {
            int n = node0 + nb + j * 4;
            if (n < N_NODES)
                xout[(size_t)n * D + od] = fmaxf(acc[j], 0.0f);
        }
    }
}

// One wave per graph: out[g] = dot(poolsum[g]/max(cnt,1), wl) + bl.
__global__ __launch_bounds__(64) void final_kernel(
    const float* __restrict__ poolsum, const float* __restrict__ cnt,
    const float* __restrict__ wl, const float* __restrict__ bl,
    float* __restrict__ out)
{
    int g = blockIdx.x;
    int d = threadIdx.x;
    float c = fmaxf(cnt[g], 1.0f);
    float v = (poolsum[g * D + d] / c) * wl[d];
    for (int off = 32; off > 0; off >>= 1)
        v += __shfl_down(v, off, 64);
    if (d == 0) out[g] = v + bl[0];
}

extern "C" void kernel_launch(void* const* d_in, const int* in_sizes, int n_in,
                              void* d_out, int out_size, void* d_ws, size_t ws_size,
                              hipStream_t stream) {
    const float* feat  = (const float*)d_in[0];
    const int*   ei    = (const int*)d_in[1];
    const int*   batch = (const int*)d_in[2];
    const float* w1a = (const float*)d_in[3];
    const float* b1a = (const float*)d_in[4];
    const float* w1b = (const float*)d_in[5];
    const float* b1b = (const float*)d_in[6];
    const float* w2a = (const float*)d_in[7];
    const float* b2a = (const float*)d_in[8];
    const float* w2b = (const float*)d_in[9];
    const float* b2b = (const float*)d_in[10];
    const float* w3a = (const float*)d_in[11];
    const float* b3a = (const float*)d_in[12];
    const float* w3b = (const float*)d_in[13];
    const float* b3b = (const float*)d_in[14];
    const float* wl  = (const float*)d_in[15];
    const float* bl  = (const float*)d_in[16];
    const int* src = ei;
    const int* dst = ei + N_EDGES;

    // workspace carve-up
    char* w = (char*)d_ws;
    float* buf0    = (float*)w;                 w += (size_t)N_NODES * D * sizeof(float);
    float* buf1    = (float*)w;                 w += (size_t)N_NODES * D * sizeof(float);
    int*   rowptr  = (int*)w;                   w += (size_t)(N_NODES + 1) * sizeof(int);
    int*   cursor  = (int*)w;                   w += (size_t)N_NODES * sizeof(int);
    int*   deg     = (int*)w;                   w += (size_t)N_NODES * sizeof(int);
    int*   eidx    = (int*)w;                   w += (size_t)N_EDGES * sizeof(int);
    int*   bsum    = (int*)w;                   w += 256 * sizeof(int);
    int*   boffs   = (int*)w;                   w += 256 * sizeof(int);
    float* poolsum = (float*)w;                 w += (size_t)N_GRAPHS * D * sizeof(float);
    float* cnt     = (float*)w;                 w += (size_t)N_GRAPHS * sizeof(float);
    float* out     = (float*)d_out;

    const int scanBlocks = (N_NODES + 255) / 256;   // 196
    const int edgeGrid   = (N_EDGES + 255) / 256;   // 3125
    const int layerGrid  = (N_NODES + NPB - 1) / NPB;

    // ---- CSR build (per call; deterministic work) ----
    hipMemsetAsync(deg, 0, (size_t)N_NODES * sizeof(int), stream);
    hist_kernel<<<edgeGrid, 256, 0, stream>>>(dst, deg);
    scan1_kernel<<<scanBlocks, 256, 0, stream>>>(deg, rowptr, bsum, N_NODES);
    scan2_kernel<<<1, 256, 0, stream>>>(bsum, boffs, scanBlocks);
    scan3_kernel<<<scanBlocks, 256, 0, stream>>>(rowptr, boffs, cursor, N_NODES);
    fill_kernel<<<edgeGrid, 256, 0, stream>>>(src, dst, cursor, eidx);

    // ---- pooling prep ----
    hipMemsetAsync(poolsum, 0, (size_t)(N_GRAPHS * D + N_GRAPHS) * sizeof(float), stream);
    count_kernel<<<scanBlocks, 256, 0, stream>>>(batch, cnt);

    // ---- 3 GIN layers (gather fused with MLP) ----
    gin_layer<<<layerGrid, 256, 0, stream>>>(feat, rowptr, eidx,
        w1a, b1a, w1b, b1b, buf0, nullptr, nullptr, 0);
    gin_layer<<<layerGrid, 256, 0, stream>>>(buf0, rowptr, eidx,
        w2a, b2a, w2b, b2b, buf1, nullptr, nullptr, 0);
    gin_layer<<<layerGrid, 256, 0, stream>>>(buf1, rowptr, eidx,
        w3a, b3a, w3b, b3b, nullptr, batch, poolsum, 1);

    final_kernel<<<N_GRAPHS, dim3(64), 0, stream>>>(poolsum, cnt, wl, bl, out);
}

// Round 3
// 263.935 us; speedup vs baseline: 8.3846x; 1.2413x over previous
//
#include <hip/hip_runtime.h>

#define N_NODES 50000
#define N_EDGES 800000
#define N_GRAPHS 512
#define D 64

// ---------------- CSR build (by dst) ----------------

__global__ __launch_bounds__(256) void hist_kernel(
    const int* __restrict__ dst, int* __restrict__ deg)
{
    int e = blockIdx.x * blockDim.x + threadIdx.x;
    if (e < N_EDGES) atomicAdd(&deg[dst[e]], 1);
}

__global__ __launch_bounds__(256) void scan1_kernel(
    const int* __restrict__ deg, int* __restrict__ excl,
    int* __restrict__ bsum, int n)
{
    __shared__ int s[256];
    int t = threadIdx.x;
    int i = blockIdx.x * 256 + t;
    int v = (i < n) ? deg[i] : 0;
    s[t] = v;
    __syncthreads();
    for (int off = 1; off < 256; off <<= 1) {
        int x = (t >= off) ? s[t - off] : 0;
        __syncthreads();
        s[t] += x;
        __syncthreads();
    }
    if (i < n) excl[i] = s[t] - v;
    if (t == 255) bsum[blockIdx.x] = s[255];
}

__global__ __launch_bounds__(256) void scan2_kernel(
    const int* __restrict__ bsum, int* __restrict__ boffs, int nblocks)
{
    __shared__ int s[256];
    int t = threadIdx.x;
    int v = (t < nblocks) ? bsum[t] : 0;
    s[t] = v;
    __syncthreads();
    for (int off = 1; off < 256; off <<= 1) {
        int x = (t >= off) ? s[t - off] : 0;
        __syncthreads();
        s[t] += x;
        __syncthreads();
    }
    if (t < nblocks) boffs[t] = s[t] - v;
}

__global__ __launch_bounds__(256) void scan3_kernel(
    int* __restrict__ rowptr, const int* __restrict__ boffs,
    int* __restrict__ cursor, int n)
{
    int i = blockIdx.x * 256 + threadIdx.x;
    if (i < n) {
        int r = rowptr[i] + boffs[blockIdx.x];
        rowptr[i] = r;
        cursor[i] = r;
    }
    if (blockIdx.x == 0 && threadIdx.x == 0) rowptr[n] = N_EDGES;
}

__global__ __launch_bounds__(256) void fill_kernel(
    const int* __restrict__ src, const int* __restrict__ dst,
    int* __restrict__ cursor, int* __restrict__ eidx)
{
    int e = blockIdx.x * blockDim.x + threadIdx.x;
    if (e < N_EDGES) {
        int pos = atomicAdd(&cursor[dst[e]], 1);
        eidx[pos] = src[e];
    }
}

// ---------------- graph start offsets (batch is sorted) ----------------
__global__ __launch_bounds__(256) void gstart_kernel(
    const int* __restrict__ batch, int* __restrict__ start)
{
    int i = blockIdx.x * 256 + threadIdx.x;
    if (i >= N_NODES) return;
    int g = batch[i];
    int gp = (i == 0) ? -1 : batch[i - 1];
    for (int gg = gp + 1; gg <= g; ++gg) start[gg] = i;
    if (i == N_NODES - 1)
        for (int gg = g + 1; gg <= N_GRAPHS; ++gg) start[gg] = N_NODES;
}

// ---------------- gather: agg[n] = x[n] + sum_{j in adj(n)} x[j] ----------------
// 16 threads/node (float4 slices), no LDS -> max occupancy; unroll 4.
__global__ __launch_bounds__(256) void gather_kernel(
    const float* __restrict__ x, const int* __restrict__ rowptr,
    const int* __restrict__ eidx, float* __restrict__ agg)
{
    int t = blockIdx.x * 256 + threadIdx.x;
    int n = t >> 4, q = t & 15;
    const float4* x4 = (const float4*)x;
    float4 acc = x4[(size_t)n * 16 + q];
    int e0 = rowptr[n], e1 = rowptr[n + 1];
    int e = e0;
    for (; e + 4 <= e1; e += 4) {
        int s0 = eidx[e], s1 = eidx[e + 1], s2 = eidx[e + 2], s3 = eidx[e + 3];
        float4 v0 = x4[(size_t)s0 * 16 + q];
        float4 v1 = x4[(size_t)s1 * 16 + q];
        float4 v2 = x4[(size_t)s2 * 16 + q];
        float4 v3 = x4[(size_t)s3 * 16 + q];
        acc.x += (v0.x + v1.x) + (v2.x + v3.x);
        acc.y += (v0.y + v1.y) + (v2.y + v3.y);
        acc.z += (v0.z + v1.z) + (v2.z + v3.z);
        acc.w += (v0.w + v1.w) + (v2.w + v3.w);
    }
    for (; e < e1; ++e) {
        float4 v = x4[(size_t)eidx[e] * 16 + q];
        acc.x += v.x; acc.y += v.y; acc.z += v.z; acc.w += v.w;
    }
    ((float4*)agg)[(size_t)n * 16 + q] = acc;
}

// ---------------- MLP: y = relu(relu(agg@wa+ba)@wb+bb) ----------------
// 64 nodes/block. sX transposed [k][n]; sW natural [k][od]. 4x4 reg tile:
// per k-step: 2x ds_read_b128 + 16 FMA. Wb prefetched to regs, written to
// sW after phase-1 barrier (sX reused for hidden). 32KB LDS.
__global__ __launch_bounds__(256) void mlp_kernel(
    const float* __restrict__ agg,
    const float* __restrict__ wa, const float* __restrict__ ba,
    const float* __restrict__ wb, const float* __restrict__ bb,
    float* __restrict__ xout)
{
    __shared__ float sX[D][D];   // [k][n], then [hk][n]
    __shared__ float sW[D][D];   // [k][od]: Wa, then Wb
    const int t = threadIdx.x;
    const int n0 = blockIdx.x * 64;

    // prefetch Wb into registers (ds-write later)
    float4 wbr[4];
    #pragma unroll
    for (int c = 0; c < 4; ++c)
        wbr[c] = ((const float4*)wb)[t + c * 256];

    // load Wa
    #pragma unroll
    for (int c = 0; c < 4; ++c)
        ((float4*)sW)[t + c * 256] = ((const float4*)wa)[t + c * 256];

    // load X transposed: thread (n = t&63, kq = t>>6) reads agg[n0+n][kq*16..+15]
    {
        int n = t & 63;
        int kq = t >> 6;
        int gn = n0 + n;
        #pragma unroll
        for (int c = 0; c < 4; ++c) {
            float4 v = make_float4(0.f, 0.f, 0.f, 0.f);
            if (gn < N_NODES)
                v = ((const float4*)agg)[(size_t)gn * 16 + kq * 4 + c];
            int k = kq * 16 + c * 4;
            sX[k + 0][n] = v.x;
            sX[k + 1][n] = v.y;
            sX[k + 2][n] = v.z;
            sX[k + 3][n] = v.w;
        }
    }
    __syncthreads();

    const int tn4 = (t & 15) * 4;   // nodes tn4..tn4+3
    const int tod = t >> 4;         // od group: od tod*4..+3
    const int tod4 = tod * 4;

    float acc[4][4];
    {
        float4 bav = ((const float4*)ba)[tod];
        #pragma unroll
        for (int i = 0; i < 4; ++i) {
            acc[i][0] = bav.x; acc[i][1] = bav.y;
            acc[i][2] = bav.z; acc[i][3] = bav.w;
        }
    }
    #pragma unroll 4
    for (int k = 0; k < D; ++k) {
        const float4 xf = *(const float4*)(&sX[k][tn4]);
        const float4 wf = *(const float4*)(&sW[k][tod4]);
        const float xv[4] = {xf.x, xf.y, xf.z, xf.w};
        const float wv[4] = {wf.x, wf.y, wf.z, wf.w};
        #pragma unroll
        for (int i = 0; i < 4; ++i)
            #pragma unroll
            for (int j = 0; j < 4; ++j)
                acc[i][j] = fmaf(xv[i], wv[j], acc[i][j]);
    }
    __syncthreads();

    // write relu(h) transposed into sX[od][n]; load Wb into sW
    #pragma unroll
    for (int j = 0; j < 4; ++j) {
        float4 hv = make_float4(fmaxf(acc[0][j], 0.f), fmaxf(acc[1][j], 0.f),
                                fmaxf(acc[2][j], 0.f), fmaxf(acc[3][j], 0.f));
        *(float4*)(&sX[tod4 + j][tn4]) = hv;
    }
    #pragma unroll
    for (int c = 0; c < 4; ++c)
        ((float4*)sW)[t + c * 256] = wbr[c];
    __syncthreads();

    {
        float4 bbv = ((const float4*)bb)[tod];
        #pragma unroll
        for (int i = 0; i < 4; ++i) {
            acc[i][0] = bbv.x; acc[i][1] = bbv.y;
            acc[i][2] = bbv.z; acc[i][3] = bbv.w;
        }
    }
    #pragma unroll 4
    for (int k = 0; k < D; ++k) {
        const float4 xf = *(const float4*)(&sX[k][tn4]);
        const float4 wf = *(const float4*)(&sW[k][tod4]);
        const float xv[4] = {xf.x, xf.y, xf.z, xf.w};
        const float wv[4] = {wf.x, wf.y, wf.z, wf.w};
        #pragma unroll
        for (int i = 0; i < 4; ++i)
            #pragma unroll
            for (int j = 0; j < 4; ++j)
                acc[i][j] = fmaf(xv[i], wv[j], acc[i][j]);
    }

    #pragma unroll
    for (int i = 0; i < 4; ++i) {
        int gn = n0 + tn4 + i;
        if (gn < N_NODES) {
            float4 ov = make_float4(fmaxf(acc[i][0], 0.f), fmaxf(acc[i][1], 0.f),
                                    fmaxf(acc[i][2], 0.f), fmaxf(acc[i][3], 0.f));
            ((float4*)xout)[(size_t)gn * 16 + tod] = ov;
        }
    }
}

// ---------------- pool + final linear: one block (64 thr) per graph ----------------
__global__ __launch_bounds__(64) void pool_kernel(
    const float* __restrict__ xf, const int* __restrict__ start,
    const float* __restrict__ wl, const float* __restrict__ bl,
    float* __restrict__ out)
{
    int g = blockIdx.x, d = threadIdx.x;
    int s = start[g], e = start[g + 1];
    float sum = 0.f;
    int i = s;
    for (; i + 4 <= e; i += 4) {
        float a = xf[(size_t)(i + 0) * D + d];
        float b = xf[(size_t)(i + 1) * D + d];
        float c = xf[(size_t)(i + 2) * D + d];
        float dd = xf[(size_t)(i + 3) * D + d];
        sum += (a + b) + (c + dd);
    }
    for (; i < e; ++i) sum += xf[(size_t)i * D + d];
    float c = fmaxf((float)(e - s), 1.0f);
    float v = (sum / c) * wl[d];
    for (int off = 32; off > 0; off >>= 1)
        v += __shfl_down(v, off, 64);
    if (d == 0) out[g] = v + bl[0];
}

extern "C" void kernel_launch(void* const* d_in, const int* in_sizes, int n_in,
                              void* d_out, int out_size, void* d_ws, size_t ws_size,
                              hipStream_t stream) {
    const float* feat  = (const float*)d_in[0];
    const int*   ei    = (const int*)d_in[1];
    const int*   batch = (const int*)d_in[2];
    const float* w1a = (const float*)d_in[3];
    const float* b1a = (const float*)d_in[4];
    const float* w1b = (const float*)d_in[5];
    const float* b1b = (const float*)d_in[6];
    const float* w2a = (const float*)d_in[7];
    const float* b2a = (const float*)d_in[8];
    const float* w2b = (const float*)d_in[9];
    const float* b2b = (const float*)d_in[10];
    const float* w3a = (const float*)d_in[11];
    const float* b3a = (const float*)d_in[12];
    const float* w3b = (const float*)d_in[13];
    const float* b3b = (const float*)d_in[14];
    const float* wl  = (const float*)d_in[15];
    const float* bl  = (const float*)d_in[16];
    const int* src = ei;
    const int* dst = ei + N_EDGES;

    char* w = (char*)d_ws;
    float* agg    = (float*)w;  w += (size_t)N_NODES * D * sizeof(float);
    float* buf0   = (float*)w;  w += (size_t)N_NODES * D * sizeof(float);
    int*   rowptr = (int*)w;    w += (size_t)(N_NODES + 1) * sizeof(int);
    int*   cursor = (int*)w;    w += (size_t)N_NODES * sizeof(int);
    int*   deg    = (int*)w;    w += (size_t)N_NODES * sizeof(int);
    int*   eidx   = (int*)w;    w += (size_t)N_EDGES * sizeof(int);
    int*   bsum   = (int*)w;    w += 256 * sizeof(int);
    int*   boffs  = (int*)w;    w += 256 * sizeof(int);
    int*   start  = (int*)w;    w += (size_t)(N_GRAPHS + 1) * sizeof(int);
    float* out    = (float*)d_out;

    const int scanBlocks = (N_NODES + 255) / 256;   // 196
    const int edgeGrid   = (N_EDGES + 255) / 256;   // 3125
    const int gatherGrid = N_NODES * 16 / 256;      // 3125 exact
    const int mlpGrid    = (N_NODES + 63) / 64;     // 782

    // CSR build
    hipMemsetAsync(deg, 0, (size_t)N_NODES * sizeof(int), stream);
    hist_kernel<<<edgeGrid, 256, 0, stream>>>(dst, deg);
    scan1_kernel<<<scanBlocks, 256, 0, stream>>>(deg, rowptr, bsum, N_NODES);
    scan2_kernel<<<1, 256, 0, stream>>>(bsum, boffs, scanBlocks);
    scan3_kernel<<<scanBlocks, 256, 0, stream>>>(rowptr, boffs, cursor, N_NODES);
    fill_kernel<<<edgeGrid, 256, 0, stream>>>(src, dst, cursor, eidx);
    gstart_kernel<<<scanBlocks, 256, 0, stream>>>(batch, start);

    // layer 1
    gather_kernel<<<gatherGrid, 256, 0, stream>>>(feat, rowptr, eidx, agg);
    mlp_kernel<<<mlpGrid, 256, 0, stream>>>(agg, w1a, b1a, w1b, b1b, buf0);
    // layer 2
    gather_kernel<<<gatherGrid, 256, 0, stream>>>(buf0, rowptr, eidx, agg);
    mlp_kernel<<<mlpGrid, 256, 0, stream>>>(agg, w2a, b2a, w2b, b2b, buf0);
    // layer 3
    gather_kernel<<<gatherGrid, 256, 0, stream>>>(buf0, rowptr, eidx, agg);
    mlp_kernel<<<mlpGrid, 256, 0, stream>>>(agg, w3a, b3a, w3b, b3b, buf0);

    pool_kernel<<<N_GRAPHS, dim3(64), 0, stream>>>(buf0, start, wl, bl, out);
}

// Round 4
// 263.754 us; speedup vs baseline: 8.3904x; 1.0007x over previous
//
#include <hip/hip_runtime.h>

#define N_NODES 50000
#define N_EDGES 800000
#define N_GRAPHS 512
#define D 64

// ---------------- CSR build (by dst) ----------------

__global__ __launch_bounds__(256) void hist_kernel(
    const int* __restrict__ dst, int* __restrict__ deg)
{
    int e = blockIdx.x * blockDim.x + threadIdx.x;
    if (e < N_EDGES) atomicAdd(&deg[dst[e]], 1);
}

__global__ __launch_bounds__(256) void scan1_kernel(
    const int* __restrict__ deg, int* __restrict__ excl,
    int* __restrict__ bsum, int n)
{
    __shared__ int s[256];
    int t = threadIdx.x;
    int i = blockIdx.x * 256 + t;
    int v = (i < n) ? deg[i] : 0;
    s[t] = v;
    __syncthreads();
    for (int off = 1; off < 256; off <<= 1) {
        int x = (t >= off) ? s[t - off] : 0;
        __syncthreads();
        s[t] += x;
        __syncthreads();
    }
    if (i < n) excl[i] = s[t] - v;
    if (t == 255) bsum[blockIdx.x] = s[255];
}

__global__ __launch_bounds__(256) void scan2_kernel(
    const int* __restrict__ bsum, int* __restrict__ boffs, int nblocks)
{
    __shared__ int s[256];
    int t = threadIdx.x;
    int v = (t < nblocks) ? bsum[t] : 0;
    s[t] = v;
    __syncthreads();
    for (int off = 1; off < 256; off <<= 1) {
        int x = (t >= off) ? s[t - off] : 0;
        __syncthreads();
        s[t] += x;
        __syncthreads();
    }
    if (t < nblocks) boffs[t] = s[t] - v;
}

__global__ __launch_bounds__(256) void scan3_kernel(
    int* __restrict__ rowptr, const int* __restrict__ boffs,
    int* __restrict__ cursor, int n)
{
    int i = blockIdx.x * 256 + threadIdx.x;
    if (i < n) {
        int r = rowptr[i] + boffs[blockIdx.x];
        rowptr[i] = r;
        cursor[i] = r;
    }
    if (blockIdx.x == 0 && threadIdx.x == 0) rowptr[n] = N_EDGES;
}

__global__ __launch_bounds__(256) void fill_kernel(
    const int* __restrict__ src, const int* __restrict__ dst,
    int* __restrict__ cursor, int* __restrict__ eidx)
{
    int e = blockIdx.x * blockDim.x + threadIdx.x;
    if (e < N_EDGES) {
        int pos = atomicAdd(&cursor[dst[e]], 1);
        eidx[pos] = src[e];
    }
}

// ---------------- graph start offsets (batch is sorted) ----------------
__global__ __launch_bounds__(256) void gstart_kernel(
    const int* __restrict__ batch, int* __restrict__ start)
{
    int i = blockIdx.x * 256 + threadIdx.x;
    if (i >= N_NODES) return;
    int g = batch[i];
    int gp = (i == 0) ? -1 : batch[i - 1];
    for (int gg = gp + 1; gg <= g; ++gg) start[gg] = i;
    if (i == N_NODES - 1)
        for (int gg = g + 1; gg <= N_GRAPHS; ++gg) start[gg] = N_NODES;
}

// ---------------- gather: agg[n] = x[n] + sum_{j in adj(n)} x[j] ----------------
// 16 threads/node (float4 slices), no LDS -> max occupancy; unroll 4.
__global__ __launch_bounds__(256) void gather_kernel(
    const float* __restrict__ x, const int* __restrict__ rowptr,
    const int* __restrict__ eidx, float* __restrict__ agg)
{
    int t = blockIdx.x * 256 + threadIdx.x;
    int n = t >> 4, q = t & 15;
    const float4* x4 = (const float4*)x;
    float4 acc = x4[(size_t)n * 16 + q];
    int e0 = rowptr[n], e1 = rowptr[n + 1];
    int e = e0;
    for (; e + 4 <= e1; e += 4) {
        int s0 = eidx[e], s1 = eidx[e + 1], s2 = eidx[e + 2], s3 = eidx[e + 3];
        float4 v0 = x4[(size_t)s0 * 16 + q];
        float4 v1 = x4[(size_t)s1 * 16 + q];
        float4 v2 = x4[(size_t)s2 * 16 + q];
        float4 v3 = x4[(size_t)s3 * 16 + q];
        acc.x += (v0.x + v1.x) + (v2.x + v3.x);
        acc.y += (v0.y + v1.y) + (v2.y + v3.y);
        acc.z += (v0.z + v1.z) + (v2.z + v3.z);
        acc.w += (v0.w + v1.w) + (v2.w + v3.w);
    }
    for (; e < e1; ++e) {
        float4 v = x4[(size_t)eidx[e] * 16 + q];
        acc.x += v.x; acc.y += v.y; acc.z += v.z; acc.w += v.w;
    }
    ((float4*)agg)[(size_t)n * 16 + q] = acc;
}

// ---------------- MLP: y = relu(relu(agg@wa+ba)@wb+bb) ----------------
// 64 nodes/block. sX transposed [k][n]; sW natural [k][od]. 4x4 reg tile:
// per k-step: 2x ds_read_b128 + 16 FMA. Wb prefetched to regs, written to
// sW after phase-1 barrier (sX reused for hidden). 32KB LDS.
__global__ __launch_bounds__(256) void mlp_kernel(
    const float* __restrict__ agg,
    const float* __restrict__ wa, const float* __restrict__ ba,
    const float* __restrict__ wb, const float* __restrict__ bb,
    float* __restrict__ xout)
{
    __shared__ float sX[D][D];   // [k][n], then [hk][n]
    __shared__ float sW[D][D];   // [k][od]: Wa, then Wb
    const int t = threadIdx.x;
    const int n0 = blockIdx.x * 64;

    // prefetch Wb into registers (ds-write later)
    float4 wbr[4];
    #pragma unroll
    for (int c = 0; c < 4; ++c)
        wbr[c] = ((const float4*)wb)[t + c * 256];

    // load Wa
    #pragma unroll
    for (int c = 0; c < 4; ++c)
        ((float4*)sW)[t + c * 256] = ((const float4*)wa)[t + c * 256];

    // load X transposed: thread (n = t&63, kq = t>>6) reads agg[n0+n][kq*16..+15]
    {
        int n = t & 63;
        int kq = t >> 6;
        int gn = n0 + n;
        #pragma unroll
        for (int c = 0; c < 4; ++c) {
            float4 v = make_float4(0.f, 0.f, 0.f, 0.f);
            if (gn < N_NODES)
                v = ((const float4*)agg)[(size_t)gn * 16 + kq * 4 + c];
            int k = kq * 16 + c * 4;
            sX[k + 0][n] = v.x;
            sX[k + 1][n] = v.y;
            sX[k + 2][n] = v.z;
            sX[k + 3][n] = v.w;
        }
    }
    __syncthreads();

    const int tn4 = (t & 15) * 4;   // nodes tn4..tn4+3
    const int tod = t >> 4;         // od group: od tod*4..+3
    const int tod4 = tod * 4;

    float acc[4][4];
    {
        float4 bav = ((const float4*)ba)[tod];
        #pragma unroll
        for (int i = 0; i < 4; ++i) {
            acc[i][0] = bav.x; acc[i][1] = bav.y;
            acc[i][2] = bav.z; acc[i][3] = bav.w;
        }
    }
    #pragma unroll 4
    for (int k = 0; k < D; ++k) {
        const float4 xf = *(const float4*)(&sX[k][tn4]);
        const float4 wf = *(const float4*)(&sW[k][tod4]);
        const float xv[4] = {xf.x, xf.y, xf.z, xf.w};
        const float wv[4] = {wf.x, wf.y, wf.z, wf.w};
        #pragma unroll
        for (int i = 0; i < 4; ++i)
            #pragma unroll
            for (int j = 0; j < 4; ++j)
                acc[i][j] = fmaf(xv[i], wv[j], acc[i][j]);
    }
    __syncthreads();

    // write relu(h) transposed into sX[od][n]; load Wb into sW
    #pragma unroll
    for (int j = 0; j < 4; ++j) {
        float4 hv = make_float4(fmaxf(acc[0][j], 0.f), fmaxf(acc[1][j], 0.f),
                                fmaxf(acc[2][j], 0.f), fmaxf(acc[3][j], 0.f));
        *(float4*)(&sX[tod4 + j][tn4]) = hv;
    }
    #pragma unroll
    for (int c = 0; c < 4; ++c)
        ((float4*)sW)[t + c * 256] = wbr[c];
    __syncthreads();

    {
        float4 bbv = ((const float4*)bb)[tod];
        #pragma unroll
        for (int i = 0; i < 4; ++i) {
            acc[i][0] = bbv.x; acc[i][1] = bbv.y;
            acc[i][2] = bbv.z; acc[i][3] = bbv.w;
        }
    }
    #pragma unroll 4
    for (int k = 0; k < D; ++k) {
        const float4 xf = *(const float4*)(&sX[k][tn4]);
        const float4 wf = *(const float4*)(&sW[k][tod4]);
        const float xv[4] = {xf.x, xf.y, xf.z, xf.w};
        const float wv[4] = {wf.x, wf.y, wf.z, wf.w};
        #pragma unroll
        for (int i = 0; i < 4; ++i)
            #pragma unroll
            for (int j = 0; j < 4; ++j)
                acc[i][j] = fmaf(xv[i], wv[j], acc[i][j]);
    }

    #pragma unroll
    for (int i = 0; i < 4; ++i) {
        int gn = n0 + tn4 + i;
        if (gn < N_NODES) {
            float4 ov = make_float4(fmaxf(acc[i][0], 0.f), fmaxf(acc[i][1], 0.f),
                                    fmaxf(acc[i][2], 0.f), fmaxf(acc[i][3], 0.f));
            ((float4*)xout)[(size_t)gn * 16 + tod] = ov;
        }
    }
}

// ---------------- pool + final linear: one block (64 thr) per graph ----------------
__global__ __launch_bounds__(64) void pool_kernel(
    const float* __restrict__ xf, const int* __restrict__ start,
    const float* __restrict__ wl, const float* __restrict__ bl,
    float* __restrict__ out)
{
    int g = blockIdx.x, d = threadIdx.x;
    int s = start[g], e = start[g + 1];
    float sum = 0.f;
    int i = s;
    for (; i + 4 <= e; i += 4) {
        float a = xf[(size_t)(i + 0) * D + d];
        float b = xf[(size_t)(i + 1) * D + d];
        float c = xf[(size_t)(i + 2) * D + d];
        float dd = xf[(size_t)(i + 3) * D + d];
        sum += (a + b) + (c + dd);
    }
    for (; i < e; ++i) sum += xf[(size_t)i * D + d];
    float c = fmaxf((float)(e - s), 1.0f);
    float v = (sum / c) * wl[d];
    for (int off = 32; off > 0; off >>= 1)
        v += __shfl_down(v, off, 64);
    if (d == 0) out[g] = v + bl[0];
}

extern "C" void kernel_launch(void* const* d_in, const int* in_sizes, int n_in,
                              void* d_out, int out_size, void* d_ws, size_t ws_size,
                              hipStream_t stream) {
    const float* feat  = (const float*)d_in[0];
    const int*   ei    = (const int*)d_in[1];
    const int*   batch = (const int*)d_in[2];
    const float* w1a = (const float*)d_in[3];
    const float* b1a = (const float*)d_in[4];
    const float* w1b = (const float*)d_in[5];
    const float* b1b = (const float*)d_in[6];
    const float* w2a = (const float*)d_in[7];
    const float* b2a = (const float*)d_in[8];
    const float* w2b = (const float*)d_in[9];
    const float* b2b = (const float*)d_in[10];
    const float* w3a = (const float*)d_in[11];
    const float* b3a = (const float*)d_in[12];
    const float* w3b = (const float*)d_in[13];
    const float* b3b = (const float*)d_in[14];
    const float* wl  = (const float*)d_in[15];
    const float* bl  = (const float*)d_in[16];
    const int* src = ei;
    const int* dst = ei + N_EDGES;

    char* w = (char*)d_ws;
    float* agg    = (float*)w;  w += (size_t)N_NODES * D * sizeof(float);
    float* buf0   = (float*)w;  w += (size_t)N_NODES * D * sizeof(float);
    int*   rowptr = (int*)w;    w += (size_t)(N_NODES + 1) * sizeof(int);
    int*   cursor = (int*)w;    w += (size_t)N_NODES * sizeof(int);
    int*   deg    = (int*)w;    w += (size_t)N_NODES * sizeof(int);
    int*   eidx   = (int*)w;    w += (size_t)N_EDGES * sizeof(int);
    int*   bsum   = (int*)w;    w += 256 * sizeof(int);
    int*   boffs  = (int*)w;    w += 256 * sizeof(int);
    int*   start  = (int*)w;    w += (size_t)(N_GRAPHS + 1) * sizeof(int);
    float* out    = (float*)d_out;

    const int scanBlocks = (N_NODES + 255) / 256;   // 196
    const int edgeGrid   = (N_EDGES + 255) / 256;   // 3125
    const int gatherGrid = N_NODES * 16 / 256;      // 3125 exact
    const int mlpGrid    = (N_NODES + 63) / 64;     // 782

    // CSR build
    hipMemsetAsync(deg, 0, (size_t)N_NODES * sizeof(int), stream);
    hist_kernel<<<edgeGrid, 256, 0, stream>>>(dst, deg);
    scan1_kernel<<<scanBlocks, 256, 0, stream>>>(deg, rowptr, bsum, N_NODES);
    scan2_kernel<<<1, 256, 0, stream>>>(bsum, boffs, scanBlocks);
    scan3_kernel<<<scanBlocks, 256, 0, stream>>>(rowptr, boffs, cursor, N_NODES);
    fill_kernel<<<edgeGrid, 256, 0, stream>>>(src, dst, cursor, eidx);
    gstart_kernel<<<scanBlocks, 256, 0, stream>>>(batch, start);

    // layer 1
    gather_kernel<<<gatherGrid, 256, 0, stream>>>(feat, rowptr, eidx, agg);
    mlp_kernel<<<mlpGrid, 256, 0, stream>>>(agg, w1a, b1a, w1b, b1b, buf0);
    // layer 2
    gather_kernel<<<gatherGrid, 256, 0, stream>>>(buf0, rowptr, eidx, agg);
    mlp_kernel<<<mlpGrid, 256, 0, stream>>>(agg, w2a, b2a, w2b, b2b, buf0);
    // layer 3
    gather_kernel<<<gatherGrid, 256, 0, stream>>>(buf0, rowptr, eidx, agg);
    mlp_kernel<<<mlpGrid, 256, 0, stream>>>(agg, w3a, b3a, w3b, b3b, buf0);

    pool_kernel<<<N_GRAPHS, dim3(64), 0, stream>>>(buf0, start, wl, bl, out);
}

// Round 5
// 227.443 us; speedup vs baseline: 9.7299x; 1.1597x over previous
//
#include <hip/hip_runtime.h>

#define N_NODES 50000
#define N_EDGES 800000
#define N_GRAPHS 512
#define D 64

// ---------------- CSR build (by dst), ONE atomic pass ----------------
// rank[e] = position of edge e within its dst row; deg = histogram.
__global__ __launch_bounds__(256) void hist_rank_kernel(
    const int* __restrict__ dst, int* __restrict__ deg, int* __restrict__ rank)
{
    int e = blockIdx.x * blockDim.x + threadIdx.x;
    if (e < N_EDGES) rank[e] = atomicAdd(&deg[dst[e]], 1);
}

__global__ __launch_bounds__(256) void scan1_kernel(
    const int* __restrict__ deg, int* __restrict__ excl,
    int* __restrict__ bsum, int n)
{
    __shared__ int s[256];
    int t = threadIdx.x;
    int i = blockIdx.x * 256 + t;
    int v = (i < n) ? deg[i] : 0;
    s[t] = v;
    __syncthreads();
    for (int off = 1; off < 256; off <<= 1) {
        int x = (t >= off) ? s[t - off] : 0;
        __syncthreads();
        s[t] += x;
        __syncthreads();
    }
    if (i < n) excl[i] = s[t] - v;
    if (t == 255) bsum[blockIdx.x] = s[255];
}

__global__ __launch_bounds__(256) void scan2_kernel(
    const int* __restrict__ bsum, int* __restrict__ boffs, int nblocks)
{
    __shared__ int s[256];
    int t = threadIdx.x;
    int v = (t < nblocks) ? bsum[t] : 0;
    s[t] = v;
    __syncthreads();
    for (int off = 1; off < 256; off <<= 1) {
        int x = (t >= off) ? s[t - off] : 0;
        __syncthreads();
        s[t] += x;
        __syncthreads();
    }
    if (t < nblocks) boffs[t] = s[t] - v;
}

__global__ __launch_bounds__(256) void scan3_kernel(
    int* __restrict__ rowptr, const int* __restrict__ boffs, int n)
{
    int i = blockIdx.x * 256 + threadIdx.x;
    if (i < n) rowptr[i] += boffs[blockIdx.x];
    if (blockIdx.x == 0 && threadIdx.x == 0) rowptr[n] = N_EDGES;
}

// Non-atomic fill: position fully determined by rowptr + rank.
__global__ __launch_bounds__(256) void fill_scatter_kernel(
    const int* __restrict__ src, const int* __restrict__ dst,
    const int* __restrict__ rank, const int* __restrict__ rowptr,
    int* __restrict__ eidx)
{
    int e = blockIdx.x * blockDim.x + threadIdx.x;
    if (e < N_EDGES) eidx[rowptr[dst[e]] + rank[e]] = src[e];
}

// ---------------- graph start offsets (batch is sorted) ----------------
__global__ __launch_bounds__(256) void gstart_kernel(
    const int* __restrict__ batch, int* __restrict__ start)
{
    int i = blockIdx.x * 256 + threadIdx.x;
    if (i >= N_NODES) return;
    int g = batch[i];
    int gp = (i == 0) ? -1 : batch[i - 1];
    for (int gg = gp + 1; gg <= g; ++gg) start[gg] = i;
    if (i == N_NODES - 1)
        for (int gg = g + 1; gg <= N_GRAPHS; ++gg) start[gg] = N_NODES;
}

// ---------------- gather: agg[n] = x[n] + sum_{j in adj(n)} x[j] ----------------
__global__ __launch_bounds__(256) void gather_kernel(
    const float* __restrict__ x, const int* __restrict__ rowptr,
    const int* __restrict__ eidx, float* __restrict__ agg)
{
    int t = blockIdx.x * 256 + threadIdx.x;
    int n = t >> 4, q = t & 15;
    const float4* x4 = (const float4*)x;
    float4 acc = x4[(size_t)n * 16 + q];
    int e0 = rowptr[n], e1 = rowptr[n + 1];
    int e = e0;
    for (; e + 4 <= e1; e += 4) {
        int s0 = eidx[e], s1 = eidx[e + 1], s2 = eidx[e + 2], s3 = eidx[e + 3];
        float4 v0 = x4[(size_t)s0 * 16 + q];
        float4 v1 = x4[(size_t)s1 * 16 + q];
        float4 v2 = x4[(size_t)s2 * 16 + q];
        float4 v3 = x4[(size_t)s3 * 16 + q];
        acc.x += (v0.x + v1.x) + (v2.x + v3.x);
        acc.y += (v0.y + v1.y) + (v2.y + v3.y);
        acc.z += (v0.z + v1.z) + (v2.z + v3.z);
        acc.w += (v0.w + v1.w) + (v2.w + v3.w);
    }
    for (; e < e1; ++e) {
        float4 v = x4[(size_t)eidx[e] * 16 + q];
        acc.x += v.x; acc.y += v.y; acc.z += v.z; acc.w += v.w;
    }
    ((float4*)agg)[(size_t)n * 16 + q] = acc;
}

// ---------------- MLP: y = relu(relu(agg@wa+ba)@wb+bb) ----------------
__global__ __launch_bounds__(256) void mlp_kernel(
    const float* __restrict__ agg,
    const float* __restrict__ wa, const float* __restrict__ ba,
    const float* __restrict__ wb, const float* __restrict__ bb,
    float* __restrict__ xout)
{
    __shared__ float sX[D][D];   // [k][n], then [hk][n]
    __shared__ float sW[D][D];   // [k][od]: Wa, then Wb
    const int t = threadIdx.x;
    const int n0 = blockIdx.x * 64;

    float4 wbr[4];
    #pragma unroll
    for (int c = 0; c < 4; ++c)
        wbr[c] = ((const float4*)wb)[t + c * 256];

    #pragma unroll
    for (int c = 0; c < 4; ++c)
        ((float4*)sW)[t + c * 256] = ((const float4*)wa)[t + c * 256];

    {
        int n = t & 63;
        int kq = t >> 6;
        int gn = n0 + n;
        #pragma unroll
        for (int c = 0; c < 4; ++c) {
            float4 v = make_float4(0.f, 0.f, 0.f, 0.f);
            if (gn < N_NODES)
                v = ((const float4*)agg)[(size_t)gn * 16 + kq * 4 + c];
            int k = kq * 16 + c * 4;
            sX[k + 0][n] = v.x;
            sX[k + 1][n] = v.y;
            sX[k + 2][n] = v.z;
            sX[k + 3][n] = v.w;
        }
    }
    __syncthreads();

    const int tn4 = (t & 15) * 4;
    const int tod = t >> 4;
    const int tod4 = tod * 4;

    float acc[4][4];
    {
        float4 bav = ((const float4*)ba)[tod];
        #pragma unroll
        for (int i = 0; i < 4; ++i) {
            acc[i][0] = bav.x; acc[i][1] = bav.y;
            acc[i][2] = bav.z; acc[i][3] = bav.w;
        }
    }
    #pragma unroll 4
    for (int k = 0; k < D; ++k) {
        const float4 xf = *(const float4*)(&sX[k][tn4]);
        const float4 wf = *(const float4*)(&sW[k][tod4]);
        const float xv[4] = {xf.x, xf.y, xf.z, xf.w};
        const float wv[4] = {wf.x, wf.y, wf.z, wf.w};
        #pragma unroll
        for (int i = 0; i < 4; ++i)
            #pragma unroll
            for (int j = 0; j < 4; ++j)
                acc[i][j] = fmaf(xv[i], wv[j], acc[i][j]);
    }
    __syncthreads();

    #pragma unroll
    for (int j = 0; j < 4; ++j) {
        float4 hv = make_float4(fmaxf(acc[0][j], 0.f), fmaxf(acc[1][j], 0.f),
                                fmaxf(acc[2][j], 0.f), fmaxf(acc[3][j], 0.f));
        *(float4*)(&sX[tod4 + j][tn4]) = hv;
    }
    #pragma unroll
    for (int c = 0; c < 4; ++c)
        ((float4*)sW)[t + c * 256] = wbr[c];
    __syncthreads();

    {
        float4 bbv = ((const float4*)bb)[tod];
        #pragma unroll
        for (int i = 0; i < 4; ++i) {
            acc[i][0] = bbv.x; acc[i][1] = bbv.y;
            acc[i][2] = bbv.z; acc[i][3] = bbv.w;
        }
    }
    #pragma unroll 4
    for (int k = 0; k < D; ++k) {
        const float4 xf = *(const float4*)(&sX[k][tn4]);
        const float4 wf = *(const float4*)(&sW[k][tod4]);
        const float xv[4] = {xf.x, xf.y, xf.z, xf.w};
        const float wv[4] = {wf.x, wf.y, wf.z, wf.w};
        #pragma unroll
        for (int i = 0; i < 4; ++i)
            #pragma unroll
            for (int j = 0; j < 4; ++j)
                acc[i][j] = fmaf(xv[i], wv[j], acc[i][j]);
    }

    #pragma unroll
    for (int i = 0; i < 4; ++i) {
        int gn = n0 + tn4 + i;
        if (gn < N_NODES) {
            float4 ov = make_float4(fmaxf(acc[i][0], 0.f), fmaxf(acc[i][1], 0.f),
                                    fmaxf(acc[i][2], 0.f), fmaxf(acc[i][3], 0.f));
            ((float4*)xout)[(size_t)gn * 16 + tod] = ov;
        }
    }
}

// ---------------- pool + final linear ----------------
__global__ __launch_bounds__(64) void pool_kernel(
    const float* __restrict__ xf, const int* __restrict__ start,
    const float* __restrict__ wl, const float* __restrict__ bl,
    float* __restrict__ out)
{
    int g = blockIdx.x, d = threadIdx.x;
    int s = start[g], e = start[g + 1];
    float sum = 0.f;
    int i = s;
    for (; i + 4 <= e; i += 4) {
        float a = xf[(size_t)(i + 0) * D + d];
        float b = xf[(size_t)(i + 1) * D + d];
        float c = xf[(size_t)(i + 2) * D + d];
        float dd = xf[(size_t)(i + 3) * D + d];
        sum += (a + b) + (c + dd);
    }
    for (; i < e; ++i) sum += xf[(size_t)i * D + d];
    float c = fmaxf((float)(e - s), 1.0f);
    float v = (sum / c) * wl[d];
    for (int off = 32; off > 0; off >>= 1)
        v += __shfl_down(v, off, 64);
    if (d == 0) out[g] = v + bl[0];
}

extern "C" void kernel_launch(void* const* d_in, const int* in_sizes, int n_in,
                              void* d_out, int out_size, void* d_ws, size_t ws_size,
                              hipStream_t stream) {
    const float* feat  = (const float*)d_in[0];
    const int*   ei    = (const int*)d_in[1];
    const int*   batch = (const int*)d_in[2];
    const float* w1a = (const float*)d_in[3];
    const float* b1a = (const float*)d_in[4];
    const float* w1b = (const float*)d_in[5];
    const float* b1b = (const float*)d_in[6];
    const float* w2a = (const float*)d_in[7];
    const float* b2a = (const float*)d_in[8];
    const float* w2b = (const float*)d_in[9];
    const float* b2b = (const float*)d_in[10];
    const float* w3a = (const float*)d_in[11];
    const float* b3a = (const float*)d_in[12];
    const float* w3b = (const float*)d_in[13];
    const float* b3b = (const float*)d_in[14];
    const float* wl  = (const float*)d_in[15];
    const float* bl  = (const float*)d_in[16];
    const int* src = ei;
    const int* dst = ei + N_EDGES;

    char* w = (char*)d_ws;
    float* agg    = (float*)w;  w += (size_t)N_NODES * D * sizeof(float);
    float* buf0   = (float*)w;  w += (size_t)N_NODES * D * sizeof(float);
    int*   rowptr = (int*)w;    w += (size_t)(N_NODES + 1) * sizeof(int);
    int*   deg    = (int*)w;    w += (size_t)N_NODES * sizeof(int);
    int*   rank   = (int*)w;    w += (size_t)N_EDGES * sizeof(int);
    int*   eidx   = (int*)w;    w += (size_t)N_EDGES * sizeof(int);
    int*   bsum   = (int*)w;    w += 256 * sizeof(int);
    int*   boffs  = (int*)w;    w += 256 * sizeof(int);
    int*   start  = (int*)w;    w += (size_t)(N_GRAPHS + 1) * sizeof(int);
    float* out    = (float*)d_out;

    const int scanBlocks = (N_NODES + 255) / 256;   // 196
    const int edgeGrid   = (N_EDGES + 255) / 256;   // 3125
    const int gatherGrid = N_NODES * 16 / 256;      // 3125 exact
    const int mlpGrid    = (N_NODES + 63) / 64;     // 782

    // CSR build: one atomic pass (hist+rank), scan, non-atomic scatter.
    hipMemsetAsync(deg, 0, (size_t)N_NODES * sizeof(int), stream);
    hist_rank_kernel<<<edgeGrid, 256, 0, stream>>>(dst, deg, rank);
    scan1_kernel<<<scanBlocks, 256, 0, stream>>>(deg, rowptr, bsum, N_NODES);
    scan2_kernel<<<1, 256, 0, stream>>>(bsum, boffs, scanBlocks);
    scan3_kernel<<<scanBlocks, 256, 0, stream>>>(rowptr, boffs, N_NODES);
    fill_scatter_kernel<<<edgeGrid, 256, 0, stream>>>(src, dst, rank, rowptr, eidx);
    gstart_kernel<<<scanBlocks, 256, 0, stream>>>(batch, start);

    // layer 1
    gather_kernel<<<gatherGrid, 256, 0, stream>>>(feat, rowptr, eidx, agg);
    mlp_kernel<<<mlpGrid, 256, 0, stream>>>(agg, w1a, b1a, w1b, b1b, buf0);
    // layer 2
    gather_kernel<<<gatherGrid, 256, 0, stream>>>(buf0, rowptr, eidx, agg);
    mlp_kernel<<<mlpGrid, 256, 0, stream>>>(agg, w2a, b2a, w2b, b2b, buf0);
    // layer 3
    gather_kernel<<<gatherGrid, 256, 0, stream>>>(buf0, rowptr, eidx, agg);
    mlp_kernel<<<mlpGrid, 256, 0, stream>>>(agg, w3a, b3a, w3b, b3b, buf0);

    pool_kernel<<<N_GRAPHS, dim3(64), 0, stream>>>(buf0, start, wl, bl, out);
}

// Round 6
// 223.601 us; speedup vs baseline: 9.8970x; 1.0172x over previous
//
#include <hip/hip_runtime.h>

#define N_NODES 50000
#define N_EDGES 800000
#define N_GRAPHS 512
#define D 64

// ---------------- zero deg (hipMemsetAsync's fill kernel costs 42us for 200KB) ----
__global__ __launch_bounds__(256) void zero_deg_kernel(int* __restrict__ deg)
{
    int i = blockIdx.x * 256 + threadIdx.x;
    if (i * 4 < N_NODES) {
        int4 z = make_int4(0, 0, 0, 0);
        ((int4*)deg)[i] = z;
    }
}

// ---------------- CSR build (by dst), ONE atomic pass ----------------
__global__ __launch_bounds__(256) void hist_rank_kernel(
    const int* __restrict__ dst, int* __restrict__ deg, int* __restrict__ rank)
{
    int e = blockIdx.x * blockDim.x + threadIdx.x;
    if (e < N_EDGES) rank[e] = atomicAdd(&deg[dst[e]], 1);
}

__global__ __launch_bounds__(256) void scan1_kernel(
    const int* __restrict__ deg, int* __restrict__ excl,
    int* __restrict__ bsum, int n)
{
    __shared__ int s[256];
    int t = threadIdx.x;
    int i = blockIdx.x * 256 + t;
    int v = (i < n) ? deg[i] : 0;
    s[t] = v;
    __syncthreads();
    for (int off = 1; off < 256; off <<= 1) {
        int x = (t >= off) ? s[t - off] : 0;
        __syncthreads();
        s[t] += x;
        __syncthreads();
    }
    if (i < n) excl[i] = s[t] - v;
    if (t == 255) bsum[blockIdx.x] = s[255];
}

__global__ __launch_bounds__(256) void scan2_kernel(
    const int* __restrict__ bsum, int* __restrict__ boffs, int nblocks)
{
    __shared__ int s[256];
    int t = threadIdx.x;
    int v = (t < nblocks) ? bsum[t] : 0;
    s[t] = v;
    __syncthreads();
    for (int off = 1; off < 256; off <<= 1) {
        int x = (t >= off) ? s[t - off] : 0;
        __syncthreads();
        s[t] += x;
        __syncthreads();
    }
    if (t < nblocks) boffs[t] = s[t] - v;
}

__global__ __launch_bounds__(256) void scan3_kernel(
    int* __restrict__ rowptr, const int* __restrict__ boffs, int n)
{
    int i = blockIdx.x * 256 + threadIdx.x;
    if (i < n) rowptr[i] += boffs[blockIdx.x];
    if (blockIdx.x == 0 && threadIdx.x == 0) rowptr[n] = N_EDGES;
}

__global__ __launch_bounds__(256) void fill_scatter_kernel(
    const int* __restrict__ src, const int* __restrict__ dst,
    const int* __restrict__ rank, const int* __restrict__ rowptr,
    int* __restrict__ eidx)
{
    int e = blockIdx.x * blockDim.x + threadIdx.x;
    if (e < N_EDGES) eidx[rowptr[dst[e]] + rank[e]] = src[e];
}

// ---------------- graph start offsets (batch is sorted) ----------------
__global__ __launch_bounds__(256) void gstart_kernel(
    const int* __restrict__ batch, int* __restrict__ start)
{
    int i = blockIdx.x * 256 + threadIdx.x;
    if (i >= N_NODES) return;
    int g = batch[i];
    int gp = (i == 0) ? -1 : batch[i - 1];
    for (int gg = gp + 1; gg <= g; ++gg) start[gg] = i;
    if (i == N_NODES - 1)
        for (int gg = g + 1; gg <= N_GRAPHS; ++gg) start[gg] = N_NODES;
}

// ---------------- gather: one WAVE per node ----------------
// wid forced to SGPR -> rowptr/eidx loads become s_load (scalar cache, no
// per-lane VMEM); x row read = one coalesced 256B global_load_dword (saddr +
// lane*4). No divergence (each wave owns exactly one node). Unroll 8 keeps
// 8 independent row-loads in flight.
__global__ __launch_bounds__(256) void gather_kernel(
    const float* __restrict__ x, const int* __restrict__ rowptr,
    const int* __restrict__ eidx, float* __restrict__ agg)
{
    const int wid = __builtin_amdgcn_readfirstlane(
        (int)((blockIdx.x * 256 + threadIdx.x) >> 6));
    const int lane = threadIdx.x & 63;

    float acc = x[(size_t)wid * D + lane];
    const int e0 = rowptr[wid], e1 = rowptr[wid + 1];
    int e = e0;
    for (; e + 8 <= e1; e += 8) {
        int s0 = eidx[e + 0], s1 = eidx[e + 1];
        int s2 = eidx[e + 2], s3 = eidx[e + 3];
        int s4 = eidx[e + 4], s5 = eidx[e + 5];
        int s6 = eidx[e + 6], s7 = eidx[e + 7];
        float v0 = x[(size_t)s0 * D + lane];
        float v1 = x[(size_t)s1 * D + lane];
        float v2 = x[(size_t)s2 * D + lane];
        float v3 = x[(size_t)s3 * D + lane];
        float v4 = x[(size_t)s4 * D + lane];
        float v5 = x[(size_t)s5 * D + lane];
        float v6 = x[(size_t)s6 * D + lane];
        float v7 = x[(size_t)s7 * D + lane];
        acc += ((v0 + v1) + (v2 + v3)) + ((v4 + v5) + (v6 + v7));
    }
    for (; e < e1; ++e)
        acc += x[(size_t)eidx[e] * D + lane];
    agg[(size_t)wid * D + lane] = acc;
}

// ---------------- MLP: y = relu(relu(agg@wa+ba)@wb+bb) ----------------
__global__ __launch_bounds__(256) void mlp_kernel(
    const float* __restrict__ agg,
    const float* __restrict__ wa, const float* __restrict__ ba,
    const float* __restrict__ wb, const float* __restrict__ bb,
    float* __restrict__ xout)
{
    __shared__ float sX[D][D];   // [k][n], then [hk][n]
    __shared__ float sW[D][D];   // [k][od]: Wa, then Wb
    const int t = threadIdx.x;
    const int n0 = blockIdx.x * 64;

    float4 wbr[4];
    #pragma unroll
    for (int c = 0; c < 4; ++c)
        wbr[c] = ((const float4*)wb)[t + c * 256];

    #pragma unroll
    for (int c = 0; c < 4; ++c)
        ((float4*)sW)[t + c * 256] = ((const float4*)wa)[t + c * 256];

    {
        int n = t & 63;
        int kq = t >> 6;
        int gn = n0 + n;
        #pragma unroll
        for (int c = 0; c < 4; ++c) {
            float4 v = make_float4(0.f, 0.f, 0.f, 0.f);
            if (gn < N_NODES)
                v = ((const float4*)agg)[(size_t)gn * 16 + kq * 4 + c];
            int k = kq * 16 + c * 4;
            sX[k + 0][n] = v.x;
            sX[k + 1][n] = v.y;
            sX[k + 2][n] = v.z;
            sX[k + 3][n] = v.w;
        }
    }
    __syncthreads();

    const int tn4 = (t & 15) * 4;
    const int tod = t >> 4;
    const int tod4 = tod * 4;

    float acc[4][4];
    {
        float4 bav = ((const float4*)ba)[tod];
        #pragma unroll
        for (int i = 0; i < 4; ++i) {
            acc[i][0] = bav.x; acc[i][1] = bav.y;
            acc[i][2] = bav.z; acc[i][3] = bav.w;
        }
    }
    #pragma unroll 4
    for (int k = 0; k < D; ++k) {
        const float4 xf = *(const float4*)(&sX[k][tn4]);
        const float4 wf = *(const float4*)(&sW[k][tod4]);
        const float xv[4] = {xf.x, xf.y, xf.z, xf.w};
        const float wv[4] = {wf.x, wf.y, wf.z, wf.w};
        #pragma unroll
        for (int i = 0; i < 4; ++i)
            #pragma unroll
            for (int j = 0; j < 4; ++j)
                acc[i][j] = fmaf(xv[i], wv[j], acc[i][j]);
    }
    __syncthreads();

    #pragma unroll
    for (int j = 0; j < 4; ++j) {
        float4 hv = make_float4(fmaxf(acc[0][j], 0.f), fmaxf(acc[1][j], 0.f),
                                fmaxf(acc[2][j], 0.f), fmaxf(acc[3][j], 0.f));
        *(float4*)(&sX[tod4 + j][tn4]) = hv;
    }
    #pragma unroll
    for (int c = 0; c < 4; ++c)
        ((float4*)sW)[t + c * 256] = wbr[c];
    __syncthreads();

    {
        float4 bbv = ((const float4*)bb)[tod];
        #pragma unroll
        for (int i = 0; i < 4; ++i) {
            acc[i][0] = bbv.x; acc[i][1] = bbv.y;
            acc[i][2] = bbv.z; acc[i][3] = bbv.w;
        }
    }
    #pragma unroll 4
    for (int k = 0; k < D; ++k) {
        const float4 xf = *(const float4*)(&sX[k][tn4]);
        const float4 wf = *(const float4*)(&sW[k][tod4]);
        const float xv[4] = {xf.x, xf.y, xf.z, xf.w};
        const float wv[4] = {wf.x, wf.y, wf.z, wf.w};
        #pragma unroll
        for (int i = 0; i < 4; ++i)
            #pragma unroll
            for (int j = 0; j < 4; ++j)
                acc[i][j] = fmaf(xv[i], wv[j], acc[i][j]);
    }

    #pragma unroll
    for (int i = 0; i < 4; ++i) {
        int gn = n0 + tn4 + i;
        if (gn < N_NODES) {
            float4 ov = make_float4(fmaxf(acc[i][0], 0.f), fmaxf(acc[i][1], 0.f),
                                    fmaxf(acc[i][2], 0.f), fmaxf(acc[i][3], 0.f));
            ((float4*)xout)[(size_t)gn * 16 + tod] = ov;
        }
    }
}

// ---------------- pool + final linear ----------------
__global__ __launch_bounds__(64) void pool_kernel(
    const float* __restrict__ xf, const int* __restrict__ start,
    const float* __restrict__ wl, const float* __restrict__ bl,
    float* __restrict__ out)
{
    int g = blockIdx.x, d = threadIdx.x;
    int s = start[g], e = start[g + 1];
    float sum = 0.f;
    int i = s;
    for (; i + 4 <= e; i += 4) {
        float a = xf[(size_t)(i + 0) * D + d];
        float b = xf[(size_t)(i + 1) * D + d];
        float c = xf[(size_t)(i + 2) * D + d];
        float dd = xf[(size_t)(i + 3) * D + d];
        sum += (a + b) + (c + dd);
    }
    for (; i < e; ++i) sum += xf[(size_t)i * D + d];
    float c = fmaxf((float)(e - s), 1.0f);
    float v = (sum / c) * wl[d];
    for (int off = 32; off > 0; off >>= 1)
        v += __shfl_down(v, off, 64);
    if (d == 0) out[g] = v + bl[0];
}

extern "C" void kernel_launch(void* const* d_in, const int* in_sizes, int n_in,
                              void* d_out, int out_size, void* d_ws, size_t ws_size,
                              hipStream_t stream) {
    const float* feat  = (const float*)d_in[0];
    const int*   ei    = (const int*)d_in[1];
    const int*   batch = (const int*)d_in[2];
    const float* w1a = (const float*)d_in[3];
    const float* b1a = (const float*)d_in[4];
    const float* w1b = (const float*)d_in[5];
    const float* b1b = (const float*)d_in[6];
    const float* w2a = (const float*)d_in[7];
    const float* b2a = (const float*)d_in[8];
    const float* w2b = (const float*)d_in[9];
    const float* b2b = (const float*)d_in[10];
    const float* w3a = (const float*)d_in[11];
    const float* b3a = (const float*)d_in[12];
    const float* w3b = (const float*)d_in[13];
    const float* b3b = (const float*)d_in[14];
    const float* wl  = (const float*)d_in[15];
    const float* bl  = (const float*)d_in[16];
    const int* src = ei;
    const int* dst = ei + N_EDGES;

    char* w = (char*)d_ws;
    float* agg    = (float*)w;  w += (size_t)N_NODES * D * sizeof(float);
    float* buf0   = (float*)w;  w += (size_t)N_NODES * D * sizeof(float);
    int*   rowptr = (int*)w;    w += (size_t)(N_NODES + 1) * sizeof(int);
    int*   deg    = (int*)w;    w += (size_t)N_NODES * sizeof(int);
    int*   rank   = (int*)w;    w += (size_t)N_EDGES * sizeof(int);
    int*   eidx   = (int*)w;    w += (size_t)N_EDGES * sizeof(int);
    int*   bsum   = (int*)w;    w += 256 * sizeof(int);
    int*   boffs  = (int*)w;    w += 256 * sizeof(int);
    int*   start  = (int*)w;    w += (size_t)(N_GRAPHS + 1) * sizeof(int);
    float* out    = (float*)d_out;

    const int scanBlocks = (N_NODES + 255) / 256;         // 196
    const int edgeGrid   = (N_EDGES + 255) / 256;         // 3125
    const int gatherGrid = N_NODES * 64 / 256;            // 12500 (1 wave/node)
    const int mlpGrid    = (N_NODES + 63) / 64;           // 782
    const int zeroGrid   = (N_NODES / 4 + 255) / 256;     // 49

    // CSR build: one atomic pass (hist+rank), scan, non-atomic scatter.
    zero_deg_kernel<<<zeroGrid, 256, 0, stream>>>(deg);
    hist_rank_kernel<<<edgeGrid, 256, 0, stream>>>(dst, deg, rank);
    scan1_kernel<<<scanBlocks, 256, 0, stream>>>(deg, rowptr, bsum, N_NODES);
    scan2_kernel<<<1, 256, 0, stream>>>(bsum, boffs, scanBlocks);
    scan3_kernel<<<scanBlocks, 256, 0, stream>>>(rowptr, boffs, N_NODES);
    fill_scatter_kernel<<<edgeGrid, 256, 0, stream>>>(src, dst, rank, rowptr, eidx);
    gstart_kernel<<<scanBlocks, 256, 0, stream>>>(batch, start);

    // layer 1
    gather_kernel<<<gatherGrid, 256, 0, stream>>>(feat, rowptr, eidx, agg);
    mlp_kernel<<<mlpGrid, 256, 0, stream>>>(agg, w1a, b1a, w1b, b1b, buf0);
    // layer 2
    gather_kernel<<<gatherGrid, 256, 0, stream>>>(buf0, rowptr, eidx, agg);
    mlp_kernel<<<mlpGrid, 256, 0, stream>>>(agg, w2a, b2a, w2b, b2b, buf0);
    // layer 3
    gather_kernel<<<gatherGrid, 256, 0, stream>>>(buf0, rowptr, eidx, agg);
    mlp_kernel<<<mlpGrid, 256, 0, stream>>>(agg, w3a, b3a, w3b, b3b, buf0);

    pool_kernel<<<N_GRAPHS, dim3(64), 0, stream>>>(buf0, start, wl, bl, out);
}